// Round 1
// baseline (410.890 us; speedup 1.0000x reference)
//
#include <hip/hip_runtime.h>

#define T 2048
#define DIM 1024
#define NE 8
#define ED 2048
#define NSLOT (T * 2)

#define BM 128
#define BN 128
#define BK 32

typedef __attribute__((ext_vector_type(8))) short s8v;   // 8 bf16 = 4 VGPRs
typedef __attribute__((ext_vector_type(4))) float f32x4; // MFMA C/D

__device__ __forceinline__ short f2bf(float f) {
    union { float f; unsigned u; } v;
    v.f = f;
    unsigned r = 0x7FFFu + ((v.u >> 16) & 1u);  // round-to-nearest-even
    v.u += r;
    return (short)(v.u >> 16);
}

// ---------------- router: 1 wave per token ----------------
__global__ void router_kernel(const float* __restrict__ x,
                              const float* __restrict__ gw,
                              const float* __restrict__ bias,
                              short* __restrict__ xb,
                              int* __restrict__ counts,
                              int* __restrict__ top2i,
                              float* __restrict__ top2w) {
    int wid = threadIdx.x >> 6;
    int lane = threadIdx.x & 63;
    int t = blockIdx.x * 4 + wid;

    const float* xr = x + (size_t)t * DIM + lane * 16;
    float4 xv[4];
#pragma unroll
    for (int j = 0; j < 4; ++j) xv[j] = *(const float4*)(xr + j * 4);

    // x -> bf16 for MFMA consumption
    s8v o0, o1;
#pragma unroll
    for (int j = 0; j < 2; ++j) {
        o0[j * 4 + 0] = f2bf(xv[j].x); o0[j * 4 + 1] = f2bf(xv[j].y);
        o0[j * 4 + 2] = f2bf(xv[j].z); o0[j * 4 + 3] = f2bf(xv[j].w);
        o1[j * 4 + 0] = f2bf(xv[j + 2].x); o1[j * 4 + 1] = f2bf(xv[j + 2].y);
        o1[j * 4 + 2] = f2bf(xv[j + 2].z); o1[j * 4 + 3] = f2bf(xv[j + 2].w);
    }
    *(s8v*)(xb + (size_t)t * DIM + lane * 16) = o0;
    *(s8v*)(xb + (size_t)t * DIM + lane * 16 + 8) = o1;

    float sc[NE];
#pragma unroll
    for (int e = 0; e < NE; ++e) {
        const float* gr = gw + e * DIM + lane * 16;
        float p = 0.f;
#pragma unroll
        for (int j = 0; j < 4; ++j) {
            float4 g = *(const float4*)(gr + j * 4);
            p += xv[j].x * g.x + xv[j].y * g.y + xv[j].z * g.z + xv[j].w * g.w;
        }
#pragma unroll
        for (int off = 32; off; off >>= 1) p += __shfl_xor(p, off, 64);
        sc[e] = 1.f / (1.f + __expf(-(p + bias[e])));
    }
    // top-2 (strict > matches jax first-index tie behavior)
    int b0 = 0; float s0 = sc[0];
#pragma unroll
    for (int e = 1; e < NE; ++e) if (sc[e] > s0) { s0 = sc[e]; b0 = e; }
    int b1 = -1; float s1 = -1e30f;
#pragma unroll
    for (int e = 0; e < NE; ++e) if (e != b0 && sc[e] > s1) { s1 = sc[e]; b1 = e; }
    float inv = 1.f / (s0 + s1 + 1e-6f);
    if (lane == 0) {
        top2i[t * 2 + 0] = b0; top2i[t * 2 + 1] = b1;
        top2w[t * 2 + 0] = s0 * inv; top2w[t * 2 + 1] = s1 * inv;
        atomicAdd(&counts[b0], 1);
        atomicAdd(&counts[b1], 1);
    }
}

__global__ void prefix_kernel(const int* __restrict__ counts, int* __restrict__ offsets) {
    if (threadIdx.x == 0) {
        int a = 0;
        for (int e = 0; e < NE; ++e) { offsets[e] = a; a += counts[e]; }
    }
}

__global__ void scatter_kernel(const int* __restrict__ top2i, const float* __restrict__ top2w,
                               const int* __restrict__ offsets, int* __restrict__ running,
                               int* __restrict__ tok_list, float* __restrict__ slot_w) {
    int t = blockIdx.x * blockDim.x + threadIdx.x;
    if (t >= T) return;
#pragma unroll
    for (int k = 0; k < 2; ++k) {
        int e = top2i[t * 2 + k];
        int pos = atomicAdd(&running[e], 1);
        tok_list[offsets[e] + pos] = t;
        slot_w[offsets[e] + pos] = top2w[t * 2 + k];
    }
}

// ---------------- grouped GEMM1: h = silu(x @ w1^T), bf16 out ----------------
__global__ __launch_bounds__(256) void ffn1_kernel(
    const short* __restrict__ xb, const float* __restrict__ w1,
    const int* __restrict__ counts, const int* __restrict__ offsets,
    const int* __restrict__ tok_list, short* __restrict__ h) {
    int e = blockIdx.z;
    int cnt = counts[e];
    int m0 = blockIdx.y * BM;
    if (m0 >= cnt) return;
    int off = offsets[e];
    int n0 = blockIdx.x * BN;

    __shared__ __align__(16) short As[4][BM][8];
    __shared__ __align__(16) short Bs[4][BN][8];

    int tid = threadIdx.x;
    int lane = tid & 63, wid = tid >> 6;
    int mo = (wid >> 1) * 64, no = (wid & 1) * 64;
    int lrow = lane & 15, lq = lane >> 4;

    f32x4 acc[4][4];
#pragma unroll
    for (int mi = 0; mi < 4; ++mi)
#pragma unroll
        for (int ni = 0; ni < 4; ++ni) acc[mi][ni] = (f32x4){0.f, 0.f, 0.f, 0.f};

    int r0 = tid >> 2, q0 = tid & 3;
    int rm0 = m0 + r0;      if (rm0 > cnt - 1) rm0 = cnt - 1;
    int rm1 = m0 + r0 + 64; if (rm1 > cnt - 1) rm1 = cnt - 1;
    int tk0 = tok_list[off + rm0];
    int tk1 = tok_list[off + rm1];
    const short* a0p = xb + (size_t)tk0 * DIM + q0 * 8;
    const short* a1p = xb + (size_t)tk1 * DIM + q0 * 8;
    const float* wb0 = w1 + ((size_t)e * ED + n0 + r0) * DIM + q0 * 8;
    const float* wb1 = wb0 + (size_t)64 * DIM;

    for (int k0 = 0; k0 < DIM; k0 += BK) {
        s8v av0 = *(const s8v*)(a0p + k0);
        s8v av1 = *(const s8v*)(a1p + k0);
        float4 f00 = *(const float4*)(wb0 + k0);
        float4 f01 = *(const float4*)(wb0 + k0 + 4);
        float4 f10 = *(const float4*)(wb1 + k0);
        float4 f11 = *(const float4*)(wb1 + k0 + 4);
        s8v bv0 = { f2bf(f00.x), f2bf(f00.y), f2bf(f00.z), f2bf(f00.w),
                    f2bf(f01.x), f2bf(f01.y), f2bf(f01.z), f2bf(f01.w) };
        s8v bv1 = { f2bf(f10.x), f2bf(f10.y), f2bf(f10.z), f2bf(f10.w),
                    f2bf(f11.x), f2bf(f11.y), f2bf(f11.z), f2bf(f11.w) };
        __syncthreads();
        *(s8v*)&As[q0][r0][0] = av0;
        *(s8v*)&As[q0][r0 + 64][0] = av1;
        *(s8v*)&Bs[q0][r0][0] = bv0;
        *(s8v*)&Bs[q0][r0 + 64][0] = bv1;
        __syncthreads();
        s8v af[4], bf[4];
#pragma unroll
        for (int mi = 0; mi < 4; ++mi) af[mi] = *(const s8v*)&As[lq][mo + mi * 16 + lrow][0];
#pragma unroll
        for (int ni = 0; ni < 4; ++ni) bf[ni] = *(const s8v*)&Bs[lq][no + ni * 16 + lrow][0];
#pragma unroll
        for (int mi = 0; mi < 4; ++mi)
#pragma unroll
            for (int ni = 0; ni < 4; ++ni)
                acc[mi][ni] = __builtin_amdgcn_mfma_f32_16x16x32_bf16(af[mi], bf[ni], acc[mi][ni], 0, 0, 0);
    }

#pragma unroll
    for (int mi = 0; mi < 4; ++mi) {
#pragma unroll
        for (int ni = 0; ni < 4; ++ni) {
            int ln = n0 + no + ni * 16 + lrow;
#pragma unroll
            for (int r = 0; r < 4; ++r) {
                int row = m0 + mo + mi * 16 + lq * 4 + r;
                if (row < cnt) {
                    float v = acc[mi][ni][r];
                    v = v / (1.f + __expf(-v));  // silu
                    h[(size_t)(off + row) * ED + ln] = f2bf(v);
                }
            }
        }
    }
}

// ---------------- grouped GEMM2: out += sw * (h @ w2^T) ----------------
__global__ __launch_bounds__(256) void ffn2_kernel(
    const short* __restrict__ h, const float* __restrict__ w2,
    const int* __restrict__ counts, const int* __restrict__ offsets,
    const int* __restrict__ tok_list, const float* __restrict__ slot_w,
    float* __restrict__ out) {
    int e = blockIdx.z;
    int cnt = counts[e];
    int m0 = blockIdx.y * BM;
    if (m0 >= cnt) return;
    int off = offsets[e];
    int n0 = blockIdx.x * BN;

    __shared__ __align__(16) short As[4][BM][8];
    __shared__ __align__(16) short Bs[4][BN][8];

    int tid = threadIdx.x;
    int lane = tid & 63, wid = tid >> 6;
    int mo = (wid >> 1) * 64, no = (wid & 1) * 64;
    int lrow = lane & 15, lq = lane >> 4;

    f32x4 acc[4][4];
#pragma unroll
    for (int mi = 0; mi < 4; ++mi)
#pragma unroll
        for (int ni = 0; ni < 4; ++ni) acc[mi][ni] = (f32x4){0.f, 0.f, 0.f, 0.f};

    int r0 = tid >> 2, q0 = tid & 3;
    int rm0 = m0 + r0;      if (rm0 > cnt - 1) rm0 = cnt - 1;
    int rm1 = m0 + r0 + 64; if (rm1 > cnt - 1) rm1 = cnt - 1;
    const short* a0p = h + (size_t)(off + rm0) * ED + q0 * 8;
    const short* a1p = h + (size_t)(off + rm1) * ED + q0 * 8;
    const float* wb0 = w2 + ((size_t)e * DIM + n0 + r0) * ED + q0 * 8;
    const float* wb1 = wb0 + (size_t)64 * ED;

    for (int k0 = 0; k0 < ED; k0 += BK) {
        s8v av0 = *(const s8v*)(a0p + k0);
        s8v av1 = *(const s8v*)(a1p + k0);
        float4 f00 = *(const float4*)(wb0 + k0);
        float4 f01 = *(const float4*)(wb0 + k0 + 4);
        float4 f10 = *(const float4*)(wb1 + k0);
        float4 f11 = *(const float4*)(wb1 + k0 + 4);
        s8v bv0 = { f2bf(f00.x), f2bf(f00.y), f2bf(f00.z), f2bf(f00.w),
                    f2bf(f01.x), f2bf(f01.y), f2bf(f01.z), f2bf(f01.w) };
        s8v bv1 = { f2bf(f10.x), f2bf(f10.y), f2bf(f10.z), f2bf(f10.w),
                    f2bf(f11.x), f2bf(f11.y), f2bf(f11.z), f2bf(f11.w) };
        __syncthreads();
        *(s8v*)&As[q0][r0][0] = av0;
        *(s8v*)&As[q0][r0 + 64][0] = av1;
        *(s8v*)&Bs[q0][r0][0] = bv0;
        *(s8v*)&Bs[q0][r0 + 64][0] = bv1;
        __syncthreads();
        s8v af[4], bf[4];
#pragma unroll
        for (int mi = 0; mi < 4; ++mi) af[mi] = *(const s8v*)&As[lq][mo + mi * 16 + lrow][0];
#pragma unroll
        for (int ni = 0; ni < 4; ++ni) bf[ni] = *(const s8v*)&Bs[lq][no + ni * 16 + lrow][0];
#pragma unroll
        for (int mi = 0; mi < 4; ++mi)
#pragma unroll
            for (int ni = 0; ni < 4; ++ni)
                acc[mi][ni] = __builtin_amdgcn_mfma_f32_16x16x32_bf16(af[mi], bf[ni], acc[mi][ni], 0, 0, 0);
    }

#pragma unroll
    for (int mi = 0; mi < 4; ++mi) {
#pragma unroll
        for (int ni = 0; ni < 4; ++ni) {
            int ln = n0 + no + ni * 16 + lrow;
#pragma unroll
            for (int r = 0; r < 4; ++r) {
                int row = m0 + mo + mi * 16 + lq * 4 + r;
                if (row < cnt) {
                    int slot = off + row;
                    int t = tok_list[slot];
                    float sw = slot_w[slot];
                    atomicAdd(&out[(size_t)t * DIM + ln], sw * acc[mi][ni][r]);
                }
            }
        }
    }
}

extern "C" void kernel_launch(void* const* d_in, const int* in_sizes, int n_in,
                              void* d_out, int out_size, void* d_ws, size_t ws_size,
                              hipStream_t stream) {
    const float* x    = (const float*)d_in[0];
    const float* gw   = (const float*)d_in[1];
    const float* bias = (const float*)d_in[2];
    const float* w1   = (const float*)d_in[3];
    const float* w2   = (const float*)d_in[4];
    float* out = (float*)d_out;

    char* ws = (char*)d_ws;
    short* xb = (short*)ws;                         // 4 MiB: x as bf16 [T][DIM]
    short* h  = (short*)(ws + (4u << 20));          // 16 MiB: h bf16 [NSLOT][ED]
    char* meta = ws + (20u << 20);
    int*   counts   = (int*)(meta);                 // [8]
    int*   running  = (int*)(meta + 32);            // [8]
    int*   offsets  = (int*)(meta + 64);            // [8]
    int*   tok_list = (int*)(meta + 96);            // [4096]
    float* slot_w   = (float*)(meta + 96 + 4 * NSLOT);
    int*   top2i    = (int*)(meta + 96 + 8 * NSLOT);        // [T*2]
    float* top2w    = (float*)(meta + 96 + 8 * NSLOT + 8 * T);

    hipMemsetAsync(d_out, 0, (size_t)T * DIM * sizeof(float), stream);
    hipMemsetAsync(meta, 0, 96, stream);

    router_kernel<<<T / 4, 256, 0, stream>>>(x, gw, bias, xb, counts, top2i, top2w);
    prefix_kernel<<<1, 64, 0, stream>>>(counts, offsets);
    scatter_kernel<<<8, 256, 0, stream>>>(top2i, top2w, offsets, running, tok_list, slot_w);
    ffn1_kernel<<<dim3(ED / BN, T / BM, NE), 256, 0, stream>>>(xb, w1, counts, offsets, tok_list, h);
    ffn2_kernel<<<dim3(DIM / BN, T / BM, NE), 256, 0, stream>>>(h, w2, counts, offsets, tok_list, slot_w, out);
}

// Round 2
// 336.313 us; speedup vs baseline: 1.2217x; 1.2217x over previous
//
#include <hip/hip_runtime.h>

#define T 2048
#define DIM 1024
#define NE 8
#define ED 2048
#define NSLOT (T * 2)
#define KSPLIT 2

#define BM 128
#define BN 128
#define BK 32

typedef __attribute__((ext_vector_type(8))) short s8v;   // 8 bf16 = 4 VGPRs
typedef __attribute__((ext_vector_type(4))) float f32x4; // MFMA C/D

__device__ __forceinline__ short f2bf(float f) {
    union { float f; unsigned u; } v;
    v.f = f;
    unsigned r = 0x7FFFu + ((v.u >> 16) & 1u);  // round-to-nearest-even
    v.u += r;
    return (short)(v.u >> 16);
}

__device__ __forceinline__ float bf2f(short s) {
    union { unsigned u; float f; } v;
    v.u = ((unsigned)(unsigned short)s) << 16;
    return v.f;
}

// ---------------- router: 1 wave per token ----------------
__global__ void router_kernel(const float* __restrict__ x,
                              const float* __restrict__ gw,
                              const float* __restrict__ bias,
                              short* __restrict__ xb,
                              int* __restrict__ counts,
                              int* __restrict__ top2i,
                              float* __restrict__ top2w) {
    int wid = threadIdx.x >> 6;
    int lane = threadIdx.x & 63;
    int t = blockIdx.x * 4 + wid;

    const float* xr = x + (size_t)t * DIM + lane * 16;
    float4 xv[4];
#pragma unroll
    for (int j = 0; j < 4; ++j) xv[j] = *(const float4*)(xr + j * 4);

    s8v o0, o1;
#pragma unroll
    for (int j = 0; j < 2; ++j) {
        o0[j * 4 + 0] = f2bf(xv[j].x); o0[j * 4 + 1] = f2bf(xv[j].y);
        o0[j * 4 + 2] = f2bf(xv[j].z); o0[j * 4 + 3] = f2bf(xv[j].w);
        o1[j * 4 + 0] = f2bf(xv[j + 2].x); o1[j * 4 + 1] = f2bf(xv[j + 2].y);
        o1[j * 4 + 2] = f2bf(xv[j + 2].z); o1[j * 4 + 3] = f2bf(xv[j + 2].w);
    }
    *(s8v*)(xb + (size_t)t * DIM + lane * 16) = o0;
    *(s8v*)(xb + (size_t)t * DIM + lane * 16 + 8) = o1;

    float sc[NE];
#pragma unroll
    for (int e = 0; e < NE; ++e) {
        const float* gr = gw + e * DIM + lane * 16;
        float p = 0.f;
#pragma unroll
        for (int j = 0; j < 4; ++j) {
            float4 g = *(const float4*)(gr + j * 4);
            p += xv[j].x * g.x + xv[j].y * g.y + xv[j].z * g.z + xv[j].w * g.w;
        }
#pragma unroll
        for (int off = 32; off; off >>= 1) p += __shfl_xor(p, off, 64);
        sc[e] = 1.f / (1.f + __expf(-(p + bias[e])));
    }
    int b0 = 0; float s0 = sc[0];
#pragma unroll
    for (int e = 1; e < NE; ++e) if (sc[e] > s0) { s0 = sc[e]; b0 = e; }
    int b1 = -1; float s1 = -1e30f;
#pragma unroll
    for (int e = 0; e < NE; ++e) if (e != b0 && sc[e] > s1) { s1 = sc[e]; b1 = e; }
    float inv = 1.f / (s0 + s1 + 1e-6f);
    if (lane == 0) {
        top2i[t * 2 + 0] = b0; top2i[t * 2 + 1] = b1;
        top2w[t * 2 + 0] = s0 * inv; top2w[t * 2 + 1] = s1 * inv;
        atomicAdd(&counts[b0], 1);
        atomicAdd(&counts[b1], 1);
    }
}

__global__ void prefix_kernel(const int* __restrict__ counts, int* __restrict__ offsets) {
    if (threadIdx.x == 0) {
        int a = 0;
        for (int e = 0; e < NE; ++e) { offsets[e] = a; a += counts[e]; }
    }
}

__global__ void scatter_kernel(const int* __restrict__ top2i,
                               const int* __restrict__ offsets, int* __restrict__ running,
                               int* __restrict__ tok_list, int* __restrict__ slot_of) {
    int t = blockIdx.x * blockDim.x + threadIdx.x;
    if (t >= T) return;
#pragma unroll
    for (int k = 0; k < 2; ++k) {
        int e = top2i[t * 2 + k];
        int pos = atomicAdd(&running[e], 1);
        int slot = offsets[e] + pos;
        tok_list[slot] = t;
        slot_of[t * 2 + k] = slot;
    }
}

// ---------------- grouped GEMM1: h = silu(x @ w1^T), bf16 out ----------------
__global__ __launch_bounds__(256) void ffn1_kernel(
    const short* __restrict__ xb, const float* __restrict__ w1,
    const int* __restrict__ counts, const int* __restrict__ offsets,
    const int* __restrict__ tok_list, short* __restrict__ h) {
    int e = blockIdx.z;
    int cnt = counts[e];
    int m0 = blockIdx.y * BM;
    if (m0 >= cnt) return;
    int off = offsets[e];
    int n0 = blockIdx.x * BN;

    __shared__ __align__(16) short As[4][BM][8];
    __shared__ __align__(16) short Bs[4][BN][8];

    int tid = threadIdx.x;
    int lane = tid & 63, wid = tid >> 6;
    int mo = (wid >> 1) * 64, no = (wid & 1) * 64;
    int lrow = lane & 15, lq = lane >> 4;

    f32x4 acc[4][4];
#pragma unroll
    for (int mi = 0; mi < 4; ++mi)
#pragma unroll
        for (int ni = 0; ni < 4; ++ni) acc[mi][ni] = (f32x4){0.f, 0.f, 0.f, 0.f};

    int r0 = tid >> 2, q0 = tid & 3;
    int rm0 = m0 + r0;      if (rm0 > cnt - 1) rm0 = cnt - 1;
    int rm1 = m0 + r0 + 64; if (rm1 > cnt - 1) rm1 = cnt - 1;
    int tk0 = tok_list[off + rm0];
    int tk1 = tok_list[off + rm1];
    const short* a0p = xb + (size_t)tk0 * DIM + q0 * 8;
    const short* a1p = xb + (size_t)tk1 * DIM + q0 * 8;
    const float* wb0 = w1 + ((size_t)e * ED + n0 + r0) * DIM + q0 * 8;
    const float* wb1 = wb0 + (size_t)64 * DIM;

    for (int k0 = 0; k0 < DIM; k0 += BK) {
        s8v av0 = *(const s8v*)(a0p + k0);
        s8v av1 = *(const s8v*)(a1p + k0);
        float4 f00 = *(const float4*)(wb0 + k0);
        float4 f01 = *(const float4*)(wb0 + k0 + 4);
        float4 f10 = *(const float4*)(wb1 + k0);
        float4 f11 = *(const float4*)(wb1 + k0 + 4);
        s8v bv0 = { f2bf(f00.x), f2bf(f00.y), f2bf(f00.z), f2bf(f00.w),
                    f2bf(f01.x), f2bf(f01.y), f2bf(f01.z), f2bf(f01.w) };
        s8v bv1 = { f2bf(f10.x), f2bf(f10.y), f2bf(f10.z), f2bf(f10.w),
                    f2bf(f11.x), f2bf(f11.y), f2bf(f11.z), f2bf(f11.w) };
        __syncthreads();
        *(s8v*)&As[q0][r0][0] = av0;
        *(s8v*)&As[q0][r0 + 64][0] = av1;
        *(s8v*)&Bs[q0][r0][0] = bv0;
        *(s8v*)&Bs[q0][r0 + 64][0] = bv1;
        __syncthreads();
        s8v af[4], bf[4];
#pragma unroll
        for (int mi = 0; mi < 4; ++mi) af[mi] = *(const s8v*)&As[lq][mo + mi * 16 + lrow][0];
#pragma unroll
        for (int ni = 0; ni < 4; ++ni) bf[ni] = *(const s8v*)&Bs[lq][no + ni * 16 + lrow][0];
#pragma unroll
        for (int mi = 0; mi < 4; ++mi)
#pragma unroll
            for (int ni = 0; ni < 4; ++ni)
                acc[mi][ni] = __builtin_amdgcn_mfma_f32_16x16x32_bf16(af[mi], bf[ni], acc[mi][ni], 0, 0, 0);
    }

#pragma unroll
    for (int mi = 0; mi < 4; ++mi) {
#pragma unroll
        for (int ni = 0; ni < 4; ++ni) {
            int ln = n0 + no + ni * 16 + lrow;
#pragma unroll
            for (int r = 0; r < 4; ++r) {
                int row = m0 + mo + mi * 16 + lq * 4 + r;
                if (row < cnt) {
                    float v = acc[mi][ni][r];
                    v = v / (1.f + __expf(-v));  // silu
                    h[(size_t)(off + row) * ED + ln] = f2bf(v);
                }
            }
        }
    }
}

// ---------------- grouped GEMM2 (K-split): eo[ks][slot] = h[slot] @ w2^T[kchunk] ----------------
__global__ __launch_bounds__(256) void ffn2_kernel(
    const short* __restrict__ h, const float* __restrict__ w2,
    const int* __restrict__ counts, const int* __restrict__ offsets,
    short* __restrict__ eo) {
    int z = blockIdx.z;
    int e = z >> 1, ks = z & 1;
    int cnt = counts[e];
    int m0 = blockIdx.y * BM;
    if (m0 >= cnt) return;
    int off = offsets[e];
    int n0 = blockIdx.x * BN;
    const int kbase = ks * (ED / KSPLIT);

    __shared__ __align__(16) short As[4][BM][8];
    __shared__ __align__(16) short Bs[4][BN][8];

    int tid = threadIdx.x;
    int lane = tid & 63, wid = tid >> 6;
    int mo = (wid >> 1) * 64, no = (wid & 1) * 64;
    int lrow = lane & 15, lq = lane >> 4;

    f32x4 acc[4][4];
#pragma unroll
    for (int mi = 0; mi < 4; ++mi)
#pragma unroll
        for (int ni = 0; ni < 4; ++ni) acc[mi][ni] = (f32x4){0.f, 0.f, 0.f, 0.f};

    int r0 = tid >> 2, q0 = tid & 3;
    int rm0 = m0 + r0;      if (rm0 > cnt - 1) rm0 = cnt - 1;
    int rm1 = m0 + r0 + 64; if (rm1 > cnt - 1) rm1 = cnt - 1;
    const short* a0p = h + (size_t)(off + rm0) * ED + q0 * 8;
    const short* a1p = h + (size_t)(off + rm1) * ED + q0 * 8;
    const float* wb0 = w2 + ((size_t)e * DIM + n0 + r0) * ED + q0 * 8;
    const float* wb1 = wb0 + (size_t)64 * ED;

    for (int k0 = kbase; k0 < kbase + ED / KSPLIT; k0 += BK) {
        s8v av0 = *(const s8v*)(a0p + k0);
        s8v av1 = *(const s8v*)(a1p + k0);
        float4 f00 = *(const float4*)(wb0 + k0);
        float4 f01 = *(const float4*)(wb0 + k0 + 4);
        float4 f10 = *(const float4*)(wb1 + k0);
        float4 f11 = *(const float4*)(wb1 + k0 + 4);
        s8v bv0 = { f2bf(f00.x), f2bf(f00.y), f2bf(f00.z), f2bf(f00.w),
                    f2bf(f01.x), f2bf(f01.y), f2bf(f01.z), f2bf(f01.w) };
        s8v bv1 = { f2bf(f10.x), f2bf(f10.y), f2bf(f10.z), f2bf(f10.w),
                    f2bf(f11.x), f2bf(f11.y), f2bf(f11.z), f2bf(f11.w) };
        __syncthreads();
        *(s8v*)&As[q0][r0][0] = av0;
        *(s8v*)&As[q0][r0 + 64][0] = av1;
        *(s8v*)&Bs[q0][r0][0] = bv0;
        *(s8v*)&Bs[q0][r0 + 64][0] = bv1;
        __syncthreads();
        s8v af[4], bf[4];
#pragma unroll
        for (int mi = 0; mi < 4; ++mi) af[mi] = *(const s8v*)&As[lq][mo + mi * 16 + lrow][0];
#pragma unroll
        for (int ni = 0; ni < 4; ++ni) bf[ni] = *(const s8v*)&Bs[lq][no + ni * 16 + lrow][0];
#pragma unroll
        for (int mi = 0; mi < 4; ++mi)
#pragma unroll
            for (int ni = 0; ni < 4; ++ni)
                acc[mi][ni] = __builtin_amdgcn_mfma_f32_16x16x32_bf16(af[mi], bf[ni], acc[mi][ni], 0, 0, 0);
    }

    short* eop = eo + (size_t)ks * NSLOT * DIM;
#pragma unroll
    for (int mi = 0; mi < 4; ++mi) {
#pragma unroll
        for (int ni = 0; ni < 4; ++ni) {
            int ln = n0 + no + ni * 16 + lrow;
#pragma unroll
            for (int r = 0; r < 4; ++r) {
                int row = m0 + mo + mi * 16 + lq * 4 + r;
                if (row < cnt) {
                    eop[(size_t)(off + row) * DIM + ln] = f2bf(acc[mi][ni][r]);
                }
            }
        }
    }
}

// ---------------- combine: out[t] = w0*(eo0[s0]+eo1[s0]) + w1*(eo0[s1]+eo1[s1]) ----------------
__global__ __launch_bounds__(256) void combine_kernel(
    const short* __restrict__ eo, const int* __restrict__ slot_of,
    const float* __restrict__ top2w, float* __restrict__ out) {
    int idx = blockIdx.x * 256 + threadIdx.x;   // T*DIM/8 threads
    int t = idx >> 7;                            // DIM/8 = 128 chunks per token
    int c = idx & 127;
    int s0 = slot_of[2 * t], s1 = slot_of[2 * t + 1];
    float w0 = top2w[2 * t], w1 = top2w[2 * t + 1];
    const short* e0 = eo;
    const short* e1 = eo + (size_t)NSLOT * DIM;
    s8v a0 = *(const s8v*)(e0 + (size_t)s0 * DIM + c * 8);
    s8v a1 = *(const s8v*)(e1 + (size_t)s0 * DIM + c * 8);
    s8v b0 = *(const s8v*)(e0 + (size_t)s1 * DIM + c * 8);
    s8v b1 = *(const s8v*)(e1 + (size_t)s1 * DIM + c * 8);
    float4 o[2];
#pragma unroll
    for (int j = 0; j < 8; ++j) {
        float v = w0 * (bf2f(a0[j]) + bf2f(a1[j])) + w1 * (bf2f(b0[j]) + bf2f(b1[j]));
        ((float*)o)[j] = v;
    }
    float4* op = (float4*)(out + (size_t)t * DIM + c * 8);
    op[0] = o[0];
    op[1] = o[1];
}

extern "C" void kernel_launch(void* const* d_in, const int* in_sizes, int n_in,
                              void* d_out, int out_size, void* d_ws, size_t ws_size,
                              hipStream_t stream) {
    const float* x    = (const float*)d_in[0];
    const float* gw   = (const float*)d_in[1];
    const float* bias = (const float*)d_in[2];
    const float* w1   = (const float*)d_in[3];
    const float* w2   = (const float*)d_in[4];
    float* out = (float*)d_out;

    char* ws = (char*)d_ws;
    short* xb = (short*)ws;                          // 4 MiB: x as bf16 [T][DIM]
    short* h  = (short*)(ws + (4u << 20));           // 16 MiB: h bf16 [NSLOT][ED]
    short* eo = (short*)(ws + (20u << 20));          // 16 MiB: eo bf16 [2][NSLOT][DIM]
    char* meta = ws + (36u << 20);
    int*   counts   = (int*)(meta);                  // [8]
    int*   running  = (int*)(meta + 32);             // [8]
    int*   offsets  = (int*)(meta + 64);             // [8]
    int*   tok_list = (int*)(meta + 96);             // [NSLOT]
    int*   slot_of  = (int*)(meta + 96 + 4 * NSLOT); // [T*2]
    int*   top2i    = (int*)(meta + 96 + 8 * NSLOT); // [T*2]
    float* top2w    = (float*)(meta + 96 + 8 * NSLOT + 8 * T);

    hipMemsetAsync(meta, 0, 64, stream);

    router_kernel<<<T / 4, 256, 0, stream>>>(x, gw, bias, xb, counts, top2i, top2w);
    prefix_kernel<<<1, 64, 0, stream>>>(counts, offsets);
    scatter_kernel<<<8, 256, 0, stream>>>(top2i, offsets, running, tok_list, slot_of);
    ffn1_kernel<<<dim3(ED / BN, T / BM, NE), 256, 0, stream>>>(xb, w1, counts, offsets, tok_list, h);
    ffn2_kernel<<<dim3(DIM / BN, T / BM, NE * KSPLIT), 256, 0, stream>>>(h, w2, counts, offsets, eo);
    combine_kernel<<<T * DIM / 8 / 256, 256, 0, stream>>>(eo, slot_of, top2w, out);
}